// Round 7
// baseline (593.365 us; speedup 1.0000x reference)
//
#include <hip/hip_runtime.h>

#define B_ 8
#define H_ 96
#define W_ 96
#define L_ (H_*W_)          // 9216
#define M_ (B_*L_)          // 73728
#define DM 192
#define DI 384
#define DS 64
#define CD 448              // DI+DS
#define NH 6
#define HD 64
#define SCALE_ 0.125f
#define LSPLIT 16           // l-chunks for attention partials (768 blocks)

typedef unsigned short bfu;
typedef __attribute__((ext_vector_type(8))) short bf16x8;
typedef __attribute__((ext_vector_type(8))) unsigned short u16x8;
typedef __attribute__((ext_vector_type(4))) float f32x4;
typedef __attribute__((ext_vector_type(2))) float f32x2;

__device__ __forceinline__ float sigm(float x){ return 1.f/(1.f+__expf(-x)); }
__device__ __forceinline__ float b2f(bfu h){ return __uint_as_float(((unsigned)h)<<16); }
__device__ __forceinline__ bfu f2b(float f){
  unsigned x = __float_as_uint(f);
  return (bfu)((x + 0x7fffu + ((x>>16)&1u)) >> 16);
}
__device__ __forceinline__ float4 ld4(const float* p){ return *(const float4*)p; }
__device__ __forceinline__ void stage8(const float* src, bfu* dst){
  float4 f0 = *(const float4*)(src), f1 = *(const float4*)(src+4);
  ushort4 a; a.x=f2b(f0.x); a.y=f2b(f0.y); a.z=f2b(f0.z); a.w=f2b(f0.w);
  ushort4 b; b.x=f2b(f1.x); b.y=f2b(f1.y); b.z=f2b(f1.z); b.w=f2b(f1.w);
  *(ushort4*)dst = a; *(ushort4*)(dst+4) = b;
}
__device__ __forceinline__ void stel(float* p, float v){ *p = v; }
__device__ __forceinline__ void stel(bfu* p, float v){ *p = f2b(v); }

// packed dual-f32 FMA: d.lo += a.lo*b.lo ; d.hi += a.hi*b.hi
__device__ __forceinline__ void pkfma(f32x2& d, f32x2 a, f32x2 b){
  asm("v_pk_fma_f32 %0, %1, %2, %0" : "+v"(d) : "v"(a), "v"(b));
}

// async global->LDS, 16B per lane; LDS dest = wave-uniform base + lane*16
__device__ __forceinline__ void gload16(const bfu* g, bfu* l){
  __builtin_amdgcn_global_load_lds(
      (const __attribute__((address_space(1))) unsigned int*)(const void*)g,
      (__attribute__((address_space(3))) unsigned int*)(void*)l, 16, 0, 0);
}

// XOR swizzle: element offset of 8-elem chunk `sg` in row `r` (16B granules)
#define SWZ(r, sg) ((((sg) ^ ((r)&7)) << 3))
// element offset of scalar col c in row r under the same swizzle
#define SWZE(r, c) (SWZ(r, (c)>>3) + ((c)&7))

// ================= MFMA GEMM: C[m,n] = sum_k A[m,k]*Bw[n,k] (+bias) =================
template<bool BIAS, class TC0, class TC1>
__global__ __launch_bounds__(256) void gemm_mfma(
    const bfu* __restrict__ A, const bfu* __restrict__ Bw,
    const float* __restrict__ bias,
    TC0* __restrict__ C0, TC1* __restrict__ C1,
    int K, int splitN, int ldc0, int ldc1,
    long sA, long sB, long sC)
{
  __shared__ alignas(16) bfu As[128][64];
  __shared__ alignas(16) bfu Bs[64][64];
  const int tid = threadIdx.x;
  const int gx = gridDim.x;
  int flat = blockIdx.y*gx + blockIdx.x;
  const int cpx = (gx*gridDim.y) >> 3;
  flat = (flat & 7)*cpx + (flat >> 3);          // bijective XCD swizzle
  const int n0 = (flat % gx)*64, m0 = (flat / gx)*128, zb = blockIdx.z;
  A  += (long)zb*sA;
  Bw += (long)zb*sB;
  const int wave = tid>>6, lane = tid&63;
  const int wr = wave>>1, wc = wave&1;
  const int lr = lane&15, lk = lane>>4;
  f32x4 acc[4][2];
  #pragma unroll
  for (int mr=0;mr<4;++mr)
    #pragma unroll
    for (int nr=0;nr<2;++nr){ acc[mr][nr][0]=0.f; acc[mr][nr][1]=0.f; acc[mr][nr][2]=0.f; acc[mr][nr][3]=0.f; }
  for (int k0 = 0; k0 < K; k0 += 64) {
    #pragma unroll
    for (int i = 0; i < 4; ++i) {
      int seg = i*256 + tid;
      int r = seg>>3, t = seg&7;
      gload16(A + (long)(m0+r)*K + k0 + ((t ^ (r&7))<<3), &As[0][0] + seg*8);
    }
    #pragma unroll
    for (int i = 0; i < 2; ++i) {
      int seg = i*256 + tid;
      int r = seg>>3, t = seg&7;
      gload16(Bw + (long)(n0+r)*K + k0 + ((t ^ (r&7))<<3), &Bs[0][0] + seg*8);
    }
    __syncthreads();
    #pragma unroll
    for (int ks = 0; ks < 2; ++ks) {
      bf16x8 af[4], bfr[2];
      #pragma unroll
      for (int mr=0; mr<4; ++mr){ int r = wr*64+mr*16+lr; af[mr]  = *(const bf16x8*)&As[r][SWZ(r, ks*4+lk)]; }
      #pragma unroll
      for (int nr=0; nr<2; ++nr){ int r = wc*32+nr*16+lr; bfr[nr] = *(const bf16x8*)&Bs[r][SWZ(r, ks*4+lk)]; }
      #pragma unroll
      for (int mr=0; mr<4; ++mr)
        #pragma unroll
        for (int nr=0; nr<2; ++nr)
          acc[mr][nr] = __builtin_amdgcn_mfma_f32_16x16x32_bf16(af[mr], bfr[nr], acc[mr][nr], 0,0,0);
    }
    __syncthreads();
  }
  #pragma unroll
  for (int mr=0; mr<4; ++mr) {
    #pragma unroll
    for (int nr=0; nr<2; ++nr) {
      const int col = n0 + wc*32 + nr*16 + lr;
      const float badd = BIAS ? bias[col] : 0.f;
      #pragma unroll
      for (int i=0;i<4;++i) {
        const int row = m0 + wr*64 + mr*16 + lk*4 + i;
        const float v = acc[mr][nr][i] + badd;
        if (col < splitN) stel(C0 + (long)zb*sC + (long)row*ldc0 + col, v);
        else              stel(C1 + (long)row*ldc1 + (col - splitN), v);
      }
    }
  }
}

// ================= u -> bf16 =================
__global__ __launch_bounds__(256) void conv_u(
    const float* __restrict__ u, bfu* __restrict__ ub)
{
  int i = blockIdx.x*256 + threadIdx.x;
  if (i >= M_*DM/8) return;
  stage8(u + (size_t)i*8, ub + (size_t)i*8);
}

// ================= weight prep =================
__global__ __launch_bounds__(256) void prep_w(
    const float* __restrict__ W_in, const float* __restrict__ pw_w,
    const float* __restrict__ W_out,
    bfu* __restrict__ Wt_in, bfu* __restrict__ pw_bf, bfu* __restrict__ Wt_out)
{
  int i = blockIdx.x*256 + threadIdx.x;
  const int n1 = 832*192, n2 = n1 + 384*384, n3 = n2 + 192*384;
  if (i < n1)      { int n=i/192, k=i%192; Wt_in[i]  = f2b(W_in[k*832+n]); }
  else if (i < n2) { int j=i-n1;           pw_bf[j]  = f2b(pw_w[j]); }
  else if (i < n3) { int j=i-n2; int n=j/384, k=j%384; Wt_out[j] = f2b(W_out[k*192+n]); }
}

// ================= depthwise conv, sliding-window, pk_fma =================
// thread = 2 channels x 4x4 pixels. 32x32 px tile, 8 channels per block.
template<int KS, int LDIN, int LDOUT, bool SILU>
__global__ __launch_bounds__(256) void conv_dw(
    const bfu* __restrict__ xin, const float* __restrict__ cw,
    const float* __restrict__ cb, bfu* __restrict__ out)
{
  constexpr int PAD = KS/2;
  constexpr int WIN = 32 + KS - 1;          // staged window
  constexpr int W4  = 4 + KS - 1;           // per-thread window
  constexpr int PLR = WIN*WIN % 32;
  constexpr int PL  = WIN*WIN + ((PLR <= 20) ? (20 - PLR) : (52 - PLR));  // PL%32==20
  __shared__ unsigned pl[4*PL];             // 4 channel-pair planes
  const int tid = threadIdx.x;
  const int tile = blockIdx.x, cg = blockIdx.y, b = blockIdx.z;
  const int h0 = (tile/3)*32, w0 = (tile%3)*32;
  const int c0 = cg*8;
  for (int i = tid; i < WIN*WIN; i += 256) {
    int y = i/WIN, x = i - y*WIN;
    int gh = h0 + y - PAD, gw = w0 + x - PAD;
    uint4 v = make_uint4(0,0,0,0);
    if ((unsigned)gh < 96u && (unsigned)gw < 96u)
      v = *(const uint4*)(xin + ((long)(b*L_ + gh*96+gw))*LDIN + c0);
    pl[0*PL + i] = v.x; pl[1*PL + i] = v.y; pl[2*PL + i] = v.z; pl[3*PL + i] = v.w;
  }
  const int cp = tid & 3, px4 = (tid>>2)&7, py4 = tid>>5;
  f32x2 w[KS*KS];
  #pragma unroll
  for (int t = 0; t < KS*KS; ++t) {
    w[t][0] = cw[(c0 + 2*cp  )*KS*KS + t];
    w[t][1] = cw[(c0 + 2*cp+1)*KS*KS + t];
  }
  f32x2 bias; bias[0] = cb[c0+2*cp]; bias[1] = cb[c0+2*cp+1];
  __syncthreads();
  f32x2 acc[4][4];
  #pragma unroll
  for (int oy=0;oy<4;++oy)
    #pragma unroll
    for (int ox=0;ox<4;++ox){ acc[oy][ox][0]=0.f; acc[oy][ox][1]=0.f; }
  const unsigned* mp = pl + cp*PL;
  const int oy0 = py4*4, ox0 = px4*4;
  #pragma unroll
  for (int wy = 0; wy < W4; ++wy) {
    f32x2 rv[W4];
    #pragma unroll
    for (int wx = 0; wx < W4; ++wx) {
      unsigned uv = mp[(oy0+wy)*WIN + ox0 + wx];
      rv[wx][0] = __uint_as_float(uv<<16);
      rv[wx][1] = __uint_as_float(uv & 0xffff0000u);
    }
    #pragma unroll
    for (int oy = 0; oy < 4; ++oy) {
      if (wy-oy >= 0 && wy-oy < KS) {
        #pragma unroll
        for (int ox = 0; ox < 4; ++ox)
          #pragma unroll
          for (int tx = 0; tx < KS; ++tx)
            pkfma(acc[oy][ox], rv[ox+tx], w[(wy-oy)*KS + tx]);
      }
    }
  }
  #pragma unroll
  for (int oy = 0; oy < 4; ++oy)
    #pragma unroll
    for (int ox = 0; ox < 4; ++ox) {
      float a0 = acc[oy][ox][0] + bias[0];
      float a1 = acc[oy][ox][1] + bias[1];
      if (SILU) { a0 = a0*sigm(a0); a1 = a1*sigm(a1); }
      unsigned o = (unsigned)f2b(a0) | ((unsigned)f2b(a1)<<16);
      long p = (long)(b*L_ + (h0+oy0+oy)*96 + (w0+ox0+ox));
      *(unsigned*)(out + p*LDOUT + c0 + 2*cp) = o;
    }
}

// ================= K_soft =================
__global__ __launch_bounds__(256) void ksoft_kernel(
    const bfu* __restrict__ xB2, bfu* __restrict__ Ksoft)
{
  int p = blockIdx.x * 4 + (threadIdx.x >> 6);
  int lane = threadIdx.x & 63;
  float v = b2f(xB2[(long)p * CD + DI + lane]);
  float k = sigm(v);
  float s = k;
  #pragma unroll
  for (int o = 32; o; o >>= 1) s += __shfl_xor(s, o);
  Ksoft[((long)p << 6) + lane] = f2b(k / (s + 1e-6f));
}

// ================= proto partials (MFMA) =================
__global__ __launch_bounds__(256) void proto_mfma(
    const bfu* __restrict__ Ksf, const bfu* __restrict__ Vs, float* __restrict__ part)
{
  const int ch = blockIdx.x, bh = blockIdx.y;
  const int b = bh / NH, hh = bh % NH;
  __shared__ alignas(16) bfu Kst[64][72];
  __shared__ alignas(16) bfu Vtt[64][72];
  const int tid = threadIdx.x;
  const int wave = tid>>6, lane = tid&63;
  const int wr = wave>>1, wc = wave&1;
  const int lr = lane&15, lk = lane>>4;
  f32x4 acc[2][2];
  #pragma unroll
  for (int mr=0;mr<2;++mr)
    #pragma unroll
    for (int nr=0;nr<2;++nr){ acc[mr][nr][0]=0.f; acc[mr][nr][1]=0.f; acc[mr][nr][2]=0.f; acc[mr][nr][3]=0.f; }
  const int lbeg = ch * (L_/LSPLIT);
  for (int l0 = lbeg; l0 < lbeg + L_/LSPLIT; l0 += 64) {
    __syncthreads();
    #pragma unroll
    for (int i=0;i<2;++i) {
      const int li = tid&63, sg = (tid>>6) + i*4;
      const long lrow = (long)b*L_ + l0 + li;
      u16x8 kv = *(const u16x8*)(Ksf + (lrow<<6) + sg*8);
      u16x8 vv = *(const u16x8*)(Vs + lrow*DI + hh*HD + sg*8);
      #pragma unroll
      for (int j=0;j<8;++j) {
        int r = sg*8+j;
        Kst[r][SWZE(r, li)] = kv[j];
        Vtt[r][SWZE(r, li)] = vv[j];
      }
    }
    __syncthreads();
    #pragma unroll
    for (int ks=0; ks<2; ++ks) {
      bf16x8 af[2], bfr[2];
      #pragma unroll
      for (int mr=0;mr<2;++mr){ int r = wr*32+mr*16+lr; af[mr]  = *(const bf16x8*)&Kst[r][SWZ(r, ks*4+lk)]; }
      #pragma unroll
      for (int nr=0;nr<2;++nr){ int r = wc*32+nr*16+lr; bfr[nr] = *(const bf16x8*)&Vtt[r][SWZ(r, ks*4+lk)]; }
      #pragma unroll
      for (int mr=0;mr<2;++mr)
        #pragma unroll
        for (int nr=0;nr<2;++nr)
          acc[mr][nr] = __builtin_amdgcn_mfma_f32_16x16x32_bf16(af[mr], bfr[nr], acc[mr][nr], 0,0,0);
    }
  }
  float* dst = part + ((long)bh*LSPLIT + ch) * 4096;
  #pragma unroll
  for (int mr=0;mr<2;++mr)
    #pragma unroll
    for (int nr=0;nr<2;++nr)
      #pragma unroll
      for (int i=0;i<4;++i) {
        int row = wr*32+mr*16+lk*4+i, col = wc*32+nr*16+lr;
        dst[row*64+col] = acc[mr][nr][i];
      }
}

// ================= reduce proto chunks -> bf16 =================
__global__ __launch_bounds__(256) void reduce_proto(
    const float* __restrict__ part, bfu* __restrict__ proto)
{
  int idx = blockIdx.x * 256 + threadIdx.x;
  int bh = idx >> 12, sd = idx & 4095;
  const float* p = part + ((long)bh*LSPLIT)*4096 + sd;
  float s = 0.f;
  #pragma unroll
  for (int c = 0; c < LSPLIT; ++c) s += p[c*4096];
  proto[idx] = f2b(s);
}

// ================= flash PV (MFMA) =================
__global__ __launch_bounds__(256) void flashpv_mfma(
    const bfu* __restrict__ proto, const bfu* __restrict__ Vs,
    float* __restrict__ pacc_part, float* __restrict__ dsum_part)
{
  const int ch = blockIdx.x, bh = blockIdx.y;
  const int b = bh / NH, hh = bh % NH;
  __shared__ alignas(16) bfu Pt[64][72];
  __shared__ alignas(16) bfu Vt[64][72];
  __shared__ alignas(16) bfu Vtt[64][72];
  __shared__ alignas(16) bfu Ptl[64][72];
  __shared__ float dsh[2][64];
  const int tid = threadIdx.x;
  const int wave = tid>>6, lane = tid&63;
  const int wr = wave>>1, wc = wave&1;
  const int lr = lane&15, lk = lane>>4;
  {
    const bfu* src = proto + ((long)bh<<12);
    #pragma unroll
    for (int i=0;i<2;++i) {
      const int li = tid&63, sg = (tid>>6) + i*4;
      *(uint4*)&Pt[li][SWZ(li, sg)] = *(const uint4*)(src + li*64 + sg*8);
    }
  }
  f32x4 pacc[2][2];
  #pragma unroll
  for (int mr=0;mr<2;++mr)
    #pragma unroll
    for (int nr=0;nr<2;++nr){ pacc[mr][nr][0]=0.f; pacc[mr][nr][1]=0.f; pacc[mr][nr][2]=0.f; pacc[mr][nr][3]=0.f; }
  float ds[8] = {};
  const int lbeg = ch * (L_/LSPLIT);
  for (int l0 = lbeg; l0 < lbeg + L_/LSPLIT; l0 += 64) {
    __syncthreads();
    #pragma unroll
    for (int i=0;i<2;++i) {
      const int li = tid&63, sg = (tid>>6) + i*4;
      u16x8 vv = *(const u16x8*)(Vs + ((long)b*L_ + l0 + li)*DI + hh*HD + sg*8);
      *(u16x8*)&Vt[li][SWZ(li, sg)] = vv;
      #pragma unroll
      for (int j=0;j<8;++j) { int r = sg*8+j; Vtt[r][SWZE(r, li)] = vv[j]; }
    }
    __syncthreads();
    f32x4 sacc[2][2];
    #pragma unroll
    for (int mr=0;mr<2;++mr)
      #pragma unroll
      for (int nr=0;nr<2;++nr){ sacc[mr][nr][0]=0.f; sacc[mr][nr][1]=0.f; sacc[mr][nr][2]=0.f; sacc[mr][nr][3]=0.f; }
    #pragma unroll
    for (int ks=0; ks<2; ++ks) {
      bf16x8 af[2], bfr[2];
      #pragma unroll
      for (int mr=0;mr<2;++mr){ int r = wr*32+mr*16+lr; af[mr]  = *(const bf16x8*)&Pt[r][SWZ(r, ks*4+lk)]; }
      #pragma unroll
      for (int nr=0;nr<2;++nr){ int r = wc*32+nr*16+lr; bfr[nr] = *(const bf16x8*)&Vt[r][SWZ(r, ks*4+lk)]; }
      #pragma unroll
      for (int mr=0;mr<2;++mr)
        #pragma unroll
        for (int nr=0;nr<2;++nr)
          sacc[mr][nr] = __builtin_amdgcn_mfma_f32_16x16x32_bf16(af[mr], bfr[nr], sacc[mr][nr], 0,0,0);
    }
    #pragma unroll
    for (int mr=0;mr<2;++mr)
      #pragma unroll
      for (int nr=0;nr<2;++nr)
        #pragma unroll
        for (int i=0;i<4;++i) {
          int row = wr*32+mr*16+lk*4+i, col = wc*32+nr*16+lr;
          float p = __expf(sacc[mr][nr][i]*SCALE_);
          ds[mr*4+i] += p;
          Ptl[row][SWZE(row, col)] = f2b(p);
        }
    __syncthreads();
    #pragma unroll
    for (int ks=0; ks<2; ++ks) {
      bf16x8 af2[2], bf2[2];
      #pragma unroll
      for (int mr=0;mr<2;++mr){ int r = wr*32+mr*16+lr; af2[mr] = *(const bf16x8*)&Ptl[r][SWZ(r, ks*4+lk)]; }
      #pragma unroll
      for (int nr=0;nr<2;++nr){ int r = wc*32+nr*16+lr; bf2[nr] = *(const bf16x8*)&Vtt[r][SWZ(r, ks*4+lk)]; }
      #pragma unroll
      for (int mr=0;mr<2;++mr)
        #pragma unroll
        for (int nr=0;nr<2;++nr)
          pacc[mr][nr] = __builtin_amdgcn_mfma_f32_16x16x32_bf16(af2[mr], bf2[nr], pacc[mr][nr], 0,0,0);
    }
  }
  float* dst = pacc_part + ((long)bh*LSPLIT + ch) * 4096;
  #pragma unroll
  for (int mr=0;mr<2;++mr)
    #pragma unroll
    for (int nr=0;nr<2;++nr)
      #pragma unroll
      for (int i=0;i<4;++i) {
        int row = wr*32+mr*16+lk*4+i, col = wc*32+nr*16+lr;
        dst[row*64+col] = pacc[mr][nr][i];
      }
  #pragma unroll
  for (int o=1;o<16;o<<=1)
    #pragma unroll
    for (int j=0;j<8;++j) ds[j] += __shfl_xor(ds[j], o);
  if (lr == 0) {
    #pragma unroll
    for (int mr=0;mr<2;++mr)
      #pragma unroll
      for (int i=0;i<4;++i)
        dsh[wc][wr*32+mr*16+lk*4+i] = ds[mr*4+i];
  }
  __syncthreads();
  if (tid < 64)
    dsum_part[((long)bh*LSPLIT + ch)*64 + tid] = dsh[0][tid] + dsh[1][tid];
}

// ================= reduce flash partials -> R2t =================
__global__ __launch_bounds__(256) void reduce_R2(
    const float* __restrict__ pacc_part, const float* __restrict__ dsum_part,
    bfu* __restrict__ R2t)
{
  int idx = blockIdx.x * 256 + threadIdx.x;
  int bh = idx >> 12, s = (idx >> 6) & 63, d = idx & 63;
  int b = bh / NH, hh = bh % NH;
  float pa = 0.f, dsv = 0.f;
  #pragma unroll
  for (int c = 0; c < LSPLIT; ++c) {
    pa += pacc_part[((long)bh*LSPLIT + c)*4096 + (s<<6) + d];
    dsv += dsum_part[((long)bh*LSPLIT + c)*64 + s];
  }
  R2t[(((long)b*DI) + hh*HD + d)*64 + s] = f2b(pa / dsv);
}

// ================= y = fine + V*D ; LN ; *z (vectorized, wave/pixel) =================
__global__ __launch_bounds__(256) void ln_kernel(
    const bfu* __restrict__ fine, const bfu* __restrict__ xB2,
    const bfu* __restrict__ z, const float* __restrict__ Dv,
    const float* __restrict__ ln_g, const float* __restrict__ ln_b,
    bfu* __restrict__ yn)
{
  const int p = blockIdx.x*4 + (threadIdx.x >> 6);
  const int lane = threadIdx.x & 63;
  float v[8]; float s = 0.f, ss = 0.f;
  if (lane < 48) {
    u16x8 fv = *(const u16x8*)(fine + (long)p*DI + lane*8);
    u16x8 xv = *(const u16x8*)(xB2 + (long)p*CD + lane*8);
    const float dv = Dv[lane >> 3];
    #pragma unroll
    for (int j=0;j<8;++j) {
      float f = b2f((bfu)fv[j]) + b2f((bfu)xv[j]) * dv;
      v[j] = f; s += f; ss += f*f;
    }
  }
  #pragma unroll
  for (int o = 32; o; o >>= 1) { s += __shfl_xor(s, o); ss += __shfl_xor(ss, o); }
  float mu = s * (1.f/384.f);
  float var = ss * (1.f/384.f) - mu*mu;
  float rs = rsqrtf(var + 1e-5f);
  if (lane < 48) {
    u16x8 zv = *(const u16x8*)(z + (long)p*DI + lane*8);
    float4 g0 = ld4(ln_g + lane*8), g1 = ld4(ln_g + lane*8 + 4);
    float4 b0 = ld4(ln_b + lane*8), b1 = ld4(ln_b + lane*8 + 4);
    float g[8] = {g0.x,g0.y,g0.z,g0.w,g1.x,g1.y,g1.z,g1.w};
    float bb[8] = {b0.x,b0.y,b0.z,b0.w,b1.x,b1.y,b1.z,b1.w};
    u16x8 ov;
    #pragma unroll
    for (int j=0;j<8;++j) {
      float o2 = (v[j] - mu) * rs * g[j] + bb[j];
      ov[j] = f2b(o2 * b2f((bfu)zv[j]));
    }
    *(u16x8*)(yn + (long)p*DI + lane*8) = ov;
  }
}

extern "C" void kernel_launch(void* const* d_in, const int* in_sizes, int n_in,
                              void* d_out, int out_size, void* d_ws, size_t ws_size,
                              hipStream_t stream) {
  const float* u      = (const float*)d_in[0];
  const float* W_in   = (const float*)d_in[1];
  const float* conv_w = (const float*)d_in[2];
  const float* conv_b = (const float*)d_in[3];
  const float* dw_w   = (const float*)d_in[4];
  const float* dw_b   = (const float*)d_in[5];
  const float* pw_w   = (const float*)d_in[6];
  const float* pw_b   = (const float*)d_in[7];
  const float* Dv     = (const float*)d_in[8];
  const float* ln_g   = (const float*)d_in[9];
  const float* ln_b   = (const float*)d_in[10];
  const float* W_out  = (const float*)d_in[11];
  float* out = (float*)d_out;

  bfu* z_bf = (bfu*)d_out;      // M_*384 bf16 == out_size*4 bytes, dead before final write

  char* ws = (char*)d_ws;
  size_t off = 0;
  bfu* xB_bf   = (bfu*)(ws + off); off += (size_t)M_*CD*2;   // gemm1 cols 384..; later fine
  bfu* xB2_bf  = (bfu*)(ws + off); off += (size_t)M_*CD*2;   // conv3 out, live to LN
  bfu* xloc_bf = (bfu*)(ws + off); off += (size_t)M_*DI*2;   // u_bf / conv5 out / part / yn
  bfu* Vs_bf   = (bfu*)(ws + off); off += (size_t)M_*DI*2;
  bfu* Ksf_bf  = (bfu*)(ws + off); off += (size_t)M_*DS*2;
  bfu* Wt_in   = (bfu*)(ws + off); off += (size_t)832*192*2;
  bfu* pw_bf   = (bfu*)(ws + off); off += (size_t)384*384*2;
  bfu* Wt_out  = (bfu*)(ws + off); off += (size_t)192*384*2;
  bfu* R2t     = (bfu*)(ws + off); off += (size_t)8*DI*64*2;
  bfu* proto_b = (bfu*)(ws + off); off += (size_t)48*4096*2;
  bfu*   u_bf  = xloc_bf;
  float* part  = (float*)xloc_bf;
  float* dsum  = part + (size_t)48*LSPLIT*4096;

  bfu* fine_bf = xB_bf;
  bfu* yn_bf   = xloc_bf;

  // 0) prep
  prep_w<<<1488, 256, 0, stream>>>(W_in, pw_w, W_out, Wt_in, pw_bf, Wt_out);
  conv_u<<<(M_*DM/8 + 255)/256, 256, 0, stream>>>(u, u_bf);
  // 1) zxB = u @ W_in
  gemm_mfma<false,bfu,bfu><<<dim3(13,576,1), 256, 0, stream>>>(
      u_bf, Wt_in, nullptr, z_bf, xB_bf, 192, 384, 384, 448, 0, 0, 0);
  // 2) depthwise 3x3 + silu
  conv_dw<3,CD,CD,true><<<dim3(9,56,8), 256, 0, stream>>>(xB_bf, conv_w, conv_b, xB2_bf);
  // 2b) K_soft
  ksoft_kernel<<<M_/4, 256, 0, stream>>>(xB2_bf, Ksf_bf);
  // 3) depthwise 5x5
  conv_dw<5,CD,DI,false><<<dim3(9,48,8), 256, 0, stream>>>(xB2_bf, dw_w, dw_b, xloc_bf);
  // 4) pointwise: Vs = xloc @ pw_w^T + pw_b
  gemm_mfma<true,bfu,bfu><<<dim3(6,576,1), 256, 0, stream>>>(
      xloc_bf, pw_bf, pw_b, Vs_bf, (bfu*)nullptr, 384, 1<<30, 384, 0, 0, 0, 0);
  // 5) proto
  proto_mfma<<<dim3(LSPLIT,48), 256, 0, stream>>>(Ksf_bf, Vs_bf, part);
  reduce_proto<<<768, 256, 0, stream>>>(part, proto_b);
  // 6) flash attention
  flashpv_mfma<<<dim3(LSPLIT,48), 256, 0, stream>>>(proto_b, Vs_bf, part, dsum);
  reduce_R2<<<768, 256, 0, stream>>>(part, dsum, R2t);
  // 7) fine = Ksoft @ refined^T
  gemm_mfma<false,bfu,bfu><<<dim3(6,72,8), 256, 0, stream>>>(
      Ksf_bf, R2t, nullptr, fine_bf, (bfu*)nullptr, 64, 1<<30, 384, 0,
      (long)L_*64, (long)DI*64, (long)L_*384);
  // 8) y = fine + V*D ; LN ; *z
  ln_kernel<<<M_/4, 256, 0, stream>>>(fine_bf, xB2_bf, z_bf, Dv, ln_g, ln_b, yn_bf);
  // 9) out = yn @ W_out
  gemm_mfma<false,float,float><<<dim3(3,576,1), 256, 0, stream>>>(
      yn_bf, Wt_out, nullptr, out, (float*)nullptr, 384, 1<<30, 192, 0, 0, 0, 0);
}

// Round 8
// 439.889 us; speedup vs baseline: 1.3489x; 1.3489x over previous
//
#include <hip/hip_runtime.h>

#define B_ 8
#define H_ 96
#define W_ 96
#define L_ (H_*W_)          // 9216
#define M_ (B_*L_)          // 73728
#define DM 192
#define DI 384
#define DS 64
#define CD 448              // DI+DS
#define NH 6
#define HD 64
#define SCALE_ 0.125f
#define LSPLIT 16           // l-chunks for attention partials (768 blocks)

typedef unsigned short bfu;
typedef __attribute__((ext_vector_type(8))) short bf16x8;
typedef __attribute__((ext_vector_type(8))) unsigned short u16x8;
typedef __attribute__((ext_vector_type(4))) float f32x4;
typedef __attribute__((ext_vector_type(2))) float f32x2;

__device__ __forceinline__ float sigm(float x){ return 1.f/(1.f+__expf(-x)); }
__device__ __forceinline__ float b2f(bfu h){ return __uint_as_float(((unsigned)h)<<16); }
__device__ __forceinline__ bfu f2b(float f){
  unsigned x = __float_as_uint(f);
  return (bfu)((x + 0x7fffu + ((x>>16)&1u)) >> 16);
}
__device__ __forceinline__ float4 ld4(const float* p){ return *(const float4*)p; }
__device__ __forceinline__ void stage8(const float* src, bfu* dst){
  float4 f0 = *(const float4*)(src), f1 = *(const float4*)(src+4);
  ushort4 a; a.x=f2b(f0.x); a.y=f2b(f0.y); a.z=f2b(f0.z); a.w=f2b(f0.w);
  ushort4 b; b.x=f2b(f1.x); b.y=f2b(f1.y); b.z=f2b(f1.z); b.w=f2b(f1.w);
  *(ushort4*)dst = a; *(ushort4*)(dst+4) = b;
}
__device__ __forceinline__ void stel(float* p, float v){ *p = v; }
__device__ __forceinline__ void stel(bfu* p, float v){ *p = f2b(v); }

// packed dual-f32 FMA: d.lo += a.lo*b.lo ; d.hi += a.hi*b.hi
__device__ __forceinline__ void pkfma(f32x2& d, f32x2 a, f32x2 b){
  asm("v_pk_fma_f32 %0, %1, %2, %0" : "+v"(d) : "v"(a), "v"(b));
}

// async global->LDS, 16B per lane
__device__ __forceinline__ void gload16(const bfu* g, bfu* l){
  __builtin_amdgcn_global_load_lds(
      (const __attribute__((address_space(1))) unsigned int*)(const void*)g,
      (__attribute__((address_space(3))) unsigned int*)(void*)l, 16, 0, 0);
}

// XOR swizzle: element offset of 8-elem chunk `sg` in row `r` (16B granules)
#define SWZ(r, sg) ((((sg) ^ ((r)&7)) << 3))
#define SWZE(r, c) (SWZ(r, (c)>>3) + ((c)&7))

// ================= MFMA GEMM: C[m,n] = sum_k A[m,k]*Bw[n,k] (+bias) =================
template<bool BIAS, class TC0, class TC1>
__global__ __launch_bounds__(256) void gemm_mfma(
    const bfu* __restrict__ A, const bfu* __restrict__ Bw,
    const float* __restrict__ bias,
    TC0* __restrict__ C0, TC1* __restrict__ C1,
    int K, int splitN, int ldc0, int ldc1,
    long sA, long sB, long sC)
{
  __shared__ alignas(16) bfu As[128][64];
  __shared__ alignas(16) bfu Bs[64][64];
  const int tid = threadIdx.x;
  const int gx = gridDim.x;
  int flat = blockIdx.y*gx + blockIdx.x;
  const int cpx = (gx*gridDim.y) >> 3;
  flat = (flat & 7)*cpx + (flat >> 3);          // bijective XCD swizzle
  const int n0 = (flat % gx)*64, m0 = (flat / gx)*128, zb = blockIdx.z;
  A  += (long)zb*sA;
  Bw += (long)zb*sB;
  const int wave = tid>>6, lane = tid&63;
  const int wr = wave>>1, wc = wave&1;
  const int lr = lane&15, lk = lane>>4;
  f32x4 acc[4][2];
  #pragma unroll
  for (int mr=0;mr<4;++mr)
    #pragma unroll
    for (int nr=0;nr<2;++nr){ acc[mr][nr][0]=0.f; acc[mr][nr][1]=0.f; acc[mr][nr][2]=0.f; acc[mr][nr][3]=0.f; }
  for (int k0 = 0; k0 < K; k0 += 64) {
    #pragma unroll
    for (int i = 0; i < 4; ++i) {
      int seg = i*256 + tid;
      int r = seg>>3, t = seg&7;
      gload16(A + (long)(m0+r)*K + k0 + ((t ^ (r&7))<<3), &As[0][0] + seg*8);
    }
    #pragma unroll
    for (int i = 0; i < 2; ++i) {
      int seg = i*256 + tid;
      int r = seg>>3, t = seg&7;
      gload16(Bw + (long)(n0+r)*K + k0 + ((t ^ (r&7))<<3), &Bs[0][0] + seg*8);
    }
    __syncthreads();
    #pragma unroll
    for (int ks = 0; ks < 2; ++ks) {
      bf16x8 af[4], bfr[2];
      #pragma unroll
      for (int mr=0; mr<4; ++mr){ int r = wr*64+mr*16+lr; af[mr]  = *(const bf16x8*)&As[r][SWZ(r, ks*4+lk)]; }
      #pragma unroll
      for (int nr=0; nr<2; ++nr){ int r = wc*32+nr*16+lr; bfr[nr] = *(const bf16x8*)&Bs[r][SWZ(r, ks*4+lk)]; }
      #pragma unroll
      for (int mr=0; mr<4; ++mr)
        #pragma unroll
        for (int nr=0; nr<2; ++nr)
          acc[mr][nr] = __builtin_amdgcn_mfma_f32_16x16x32_bf16(af[mr], bfr[nr], acc[mr][nr], 0,0,0);
    }
    __syncthreads();
  }
  #pragma unroll
  for (int mr=0; mr<4; ++mr) {
    #pragma unroll
    for (int nr=0; nr<2; ++nr) {
      const int col = n0 + wc*32 + nr*16 + lr;
      const float badd = BIAS ? bias[col] : 0.f;
      #pragma unroll
      for (int i=0;i<4;++i) {
        const int row = m0 + wr*64 + mr*16 + lk*4 + i;
        const float v = acc[mr][nr][i] + badd;
        if (col < splitN) stel(C0 + (long)zb*sC + (long)row*ldc0 + col, v);
        else              stel(C1 + (long)row*ldc1 + (col - splitN), v);
      }
    }
  }
}

// ================= u -> bf16 =================
__global__ __launch_bounds__(256) void conv_u(
    const float* __restrict__ u, bfu* __restrict__ ub)
{
  int i = blockIdx.x*256 + threadIdx.x;
  if (i >= M_*DM/8) return;
  stage8(u + (size_t)i*8, ub + (size_t)i*8);
}

// ================= weight prep =================
__global__ __launch_bounds__(256) void prep_w(
    const float* __restrict__ W_in, const float* __restrict__ pw_w,
    const float* __restrict__ W_out,
    bfu* __restrict__ Wt_in, bfu* __restrict__ pw_bf, bfu* __restrict__ Wt_out)
{
  int i = blockIdx.x*256 + threadIdx.x;
  const int n1 = 832*192, n2 = n1 + 384*384, n3 = n2 + 192*384;
  if (i < n1)      { int n=i/192, k=i%192; Wt_in[i]  = f2b(W_in[k*832+n]); }
  else if (i < n2) { int j=i-n1;           pw_bf[j]  = f2b(pw_w[j]); }
  else if (i < n3) { int j=i-n2; int n=j/384, k=j%384; Wt_out[j] = f2b(W_out[k*192+n]); }
}

// ================= depthwise conv: 32 ch/block (full 64B lines), 16x16 tile =================
// thread = 2 channels x 4x4 pixels. 16 channel-pair LDS planes.
template<int KS, int LDIN, int LDOUT, bool SILU>
__global__ __launch_bounds__(256) void conv_dw(
    const bfu* __restrict__ xin, const float* __restrict__ cw,
    const float* __restrict__ cb, bfu* __restrict__ out)
{
  constexpr int PAD = KS/2;
  constexpr int WIN = 16 + KS - 1;
  constexpr int W4  = 4 + KS - 1;
  constexpr int PLR = (WIN*WIN) % 32;
  constexpr int PL  = WIN*WIN + ((PLR <= 2) ? (2 - PLR) : (34 - PLR));  // PL%32==2
  __shared__ unsigned pl[16*PL];            // 16 channel-pair planes
  const int tid = threadIdx.x;
  const int tile = blockIdx.x, cg = blockIdx.y, b = blockIdx.z;
  const int h0 = (tile/6)*16, w0 = (tile%6)*16;
  const int c0 = cg*32;
  for (int i = tid; i < WIN*WIN*4; i += 256) {
    int px = i >> 2, q = i & 3;
    int y = px/WIN, x = px - y*WIN;
    int gh = h0 + y - PAD, gw = w0 + x - PAD;
    uint4 v = make_uint4(0,0,0,0);
    if ((unsigned)gh < 96u && (unsigned)gw < 96u)
      v = *(const uint4*)(xin + ((long)(b*L_ + gh*96+gw))*LDIN + c0 + q*8);
    pl[(q*4+0)*PL + px] = v.x;
    pl[(q*4+1)*PL + px] = v.y;
    pl[(q*4+2)*PL + px] = v.z;
    pl[(q*4+3)*PL + px] = v.w;
  }
  const int cp = tid & 15, pos = tid >> 4;
  const int px4 = pos & 3, py4 = pos >> 2;
  f32x2 w[KS*KS];
  #pragma unroll
  for (int t = 0; t < KS*KS; ++t) {
    w[t][0] = cw[(c0 + 2*cp  )*KS*KS + t];
    w[t][1] = cw[(c0 + 2*cp+1)*KS*KS + t];
  }
  f32x2 bias; bias[0] = cb[c0+2*cp]; bias[1] = cb[c0+2*cp+1];
  __syncthreads();
  f32x2 acc[4][4];
  #pragma unroll
  for (int oy=0;oy<4;++oy)
    #pragma unroll
    for (int ox=0;ox<4;++ox){ acc[oy][ox][0]=0.f; acc[oy][ox][1]=0.f; }
  const unsigned* mp = pl + cp*PL;
  const int oy0 = py4*4, ox0 = px4*4;
  #pragma unroll
  for (int wy = 0; wy < W4; ++wy) {
    f32x2 rv[W4];
    #pragma unroll
    for (int wx = 0; wx < W4; ++wx) {
      unsigned uv = mp[(oy0+wy)*WIN + ox0 + wx];
      rv[wx][0] = __uint_as_float(uv<<16);
      rv[wx][1] = __uint_as_float(uv & 0xffff0000u);
    }
    #pragma unroll
    for (int oy = 0; oy < 4; ++oy) {
      if (wy-oy >= 0 && wy-oy < KS) {
        #pragma unroll
        for (int ox = 0; ox < 4; ++ox)
          #pragma unroll
          for (int tx = 0; tx < KS; ++tx)
            pkfma(acc[oy][ox], rv[ox+tx], w[(wy-oy)*KS + tx]);
      }
    }
  }
  #pragma unroll
  for (int oy = 0; oy < 4; ++oy)
    #pragma unroll
    for (int ox = 0; ox < 4; ++ox) {
      float a0 = acc[oy][ox][0] + bias[0];
      float a1 = acc[oy][ox][1] + bias[1];
      if (SILU) { a0 = a0*sigm(a0); a1 = a1*sigm(a1); }
      unsigned o = (unsigned)f2b(a0) | ((unsigned)f2b(a1)<<16);
      long p = (long)(b*L_ + (h0+oy0+oy)*96 + (w0+ox0+ox));
      *(unsigned*)(out + p*LDOUT + c0 + 2*cp) = o;
    }
}

// ================= K_soft =================
__global__ __launch_bounds__(256) void ksoft_kernel(
    const bfu* __restrict__ xB2, bfu* __restrict__ Ksoft)
{
  int p = blockIdx.x * 4 + (threadIdx.x >> 6);
  int lane = threadIdx.x & 63;
  float v = b2f(xB2[(long)p * CD + DI + lane]);
  float k = sigm(v);
  float s = k;
  #pragma unroll
  for (int o = 32; o; o >>= 1) s += __shfl_xor(s, o);
  Ksoft[((long)p << 6) + lane] = f2b(k / (s + 1e-6f));
}

// ================= proto partials (MFMA) =================
__global__ __launch_bounds__(256) void proto_mfma(
    const bfu* __restrict__ Ksf, const bfu* __restrict__ Vs, float* __restrict__ part)
{
  const int ch = blockIdx.x, bh = blockIdx.y;
  const int b = bh / NH, hh = bh % NH;
  __shared__ alignas(16) bfu Kst[64][72];
  __shared__ alignas(16) bfu Vtt[64][72];
  const int tid = threadIdx.x;
  const int wave = tid>>6, lane = tid&63;
  const int wr = wave>>1, wc = wave&1;
  const int lr = lane&15, lk = lane>>4;
  f32x4 acc[2][2];
  #pragma unroll
  for (int mr=0;mr<2;++mr)
    #pragma unroll
    for (int nr=0;nr<2;++nr){ acc[mr][nr][0]=0.f; acc[mr][nr][1]=0.f; acc[mr][nr][2]=0.f; acc[mr][nr][3]=0.f; }
  const int lbeg = ch * (L_/LSPLIT);
  for (int l0 = lbeg; l0 < lbeg + L_/LSPLIT; l0 += 64) {
    __syncthreads();
    #pragma unroll
    for (int i=0;i<2;++i) {
      const int li = tid&63, sg = (tid>>6) + i*4;
      const long lrow = (long)b*L_ + l0 + li;
      u16x8 kv = *(const u16x8*)(Ksf + (lrow<<6) + sg*8);
      u16x8 vv = *(const u16x8*)(Vs + lrow*DI + hh*HD + sg*8);
      #pragma unroll
      for (int j=0;j<8;++j) {
        int r = sg*8+j;
        Kst[r][SWZE(r, li)] = kv[j];
        Vtt[r][SWZE(r, li)] = vv[j];
      }
    }
    __syncthreads();
    #pragma unroll
    for (int ks=0; ks<2; ++ks) {
      bf16x8 af[2], bfr[2];
      #pragma unroll
      for (int mr=0;mr<2;++mr){ int r = wr*32+mr*16+lr; af[mr]  = *(const bf16x8*)&Kst[r][SWZ(r, ks*4+lk)]; }
      #pragma unroll
      for (int nr=0;nr<2;++nr){ int r = wc*32+nr*16+lr; bfr[nr] = *(const bf16x8*)&Vtt[r][SWZ(r, ks*4+lk)]; }
      #pragma unroll
      for (int mr=0;mr<2;++mr)
        #pragma unroll
        for (int nr=0;nr<2;++nr)
          acc[mr][nr] = __builtin_amdgcn_mfma_f32_16x16x32_bf16(af[mr], bfr[nr], acc[mr][nr], 0,0,0);
    }
  }
  float* dst = part + ((long)bh*LSPLIT + ch) * 4096;
  #pragma unroll
  for (int mr=0;mr<2;++mr)
    #pragma unroll
    for (int nr=0;nr<2;++nr)
      #pragma unroll
      for (int i=0;i<4;++i) {
        int row = wr*32+mr*16+lk*4+i, col = wc*32+nr*16+lr;
        dst[row*64+col] = acc[mr][nr][i];
      }
}

// ================= reduce proto chunks -> bf16 =================
__global__ __launch_bounds__(256) void reduce_proto(
    const float* __restrict__ part, bfu* __restrict__ proto)
{
  int idx = blockIdx.x * 256 + threadIdx.x;
  int bh = idx >> 12, sd = idx & 4095;
  const float* p = part + ((long)bh*LSPLIT)*4096 + sd;
  float s = 0.f;
  #pragma unroll
  for (int c = 0; c < LSPLIT; ++c) s += p[c*4096];
  proto[idx] = f2b(s);
}

// ================= flash PV (MFMA) =================
__global__ __launch_bounds__(256) void flashpv_mfma(
    const bfu* __restrict__ proto, const bfu* __restrict__ Vs,
    float* __restrict__ pacc_part, float* __restrict__ dsum_part)
{
  const int ch = blockIdx.x, bh = blockIdx.y;
  const int b = bh / NH, hh = bh % NH;
  __shared__ alignas(16) bfu Pt[64][72];
  __shared__ alignas(16) bfu Vt[64][72];
  __shared__ alignas(16) bfu Vtt[64][72];
  __shared__ alignas(16) bfu Ptl[64][72];
  __shared__ float dsh[2][64];
  const int tid = threadIdx.x;
  const int wave = tid>>6, lane = tid&63;
  const int wr = wave>>1, wc = wave&1;
  const int lr = lane&15, lk = lane>>4;
  {
    const bfu* src = proto + ((long)bh<<12);
    #pragma unroll
    for (int i=0;i<2;++i) {
      const int li = tid&63, sg = (tid>>6) + i*4;
      *(uint4*)&Pt[li][SWZ(li, sg)] = *(const uint4*)(src + li*64 + sg*8);
    }
  }
  f32x4 pacc[2][2];
  #pragma unroll
  for (int mr=0;mr<2;++mr)
    #pragma unroll
    for (int nr=0;nr<2;++nr){ pacc[mr][nr][0]=0.f; pacc[mr][nr][1]=0.f; pacc[mr][nr][2]=0.f; pacc[mr][nr][3]=0.f; }
  float ds[8] = {};
  const int lbeg = ch * (L_/LSPLIT);
  for (int l0 = lbeg; l0 < lbeg + L_/LSPLIT; l0 += 64) {
    __syncthreads();
    #pragma unroll
    for (int i=0;i<2;++i) {
      const int li = tid&63, sg = (tid>>6) + i*4;
      u16x8 vv = *(const u16x8*)(Vs + ((long)b*L_ + l0 + li)*DI + hh*HD + sg*8);
      *(u16x8*)&Vt[li][SWZ(li, sg)] = vv;
      #pragma unroll
      for (int j=0;j<8;++j) { int r = sg*8+j; Vtt[r][SWZE(r, li)] = vv[j]; }
    }
    __syncthreads();
    f32x4 sacc[2][2];
    #pragma unroll
    for (int mr=0;mr<2;++mr)
      #pragma unroll
      for (int nr=0;nr<2;++nr){ sacc[mr][nr][0]=0.f; sacc[mr][nr][1]=0.f; sacc[mr][nr][2]=0.f; sacc[mr][nr][3]=0.f; }
    #pragma unroll
    for (int ks=0; ks<2; ++ks) {
      bf16x8 af[2], bfr[2];
      #pragma unroll
      for (int mr=0;mr<2;++mr){ int r = wr*32+mr*16+lr; af[mr]  = *(const bf16x8*)&Pt[r][SWZ(r, ks*4+lk)]; }
      #pragma unroll
      for (int nr=0;nr<2;++nr){ int r = wc*32+nr*16+lr; bfr[nr] = *(const bf16x8*)&Vt[r][SWZ(r, ks*4+lk)]; }
      #pragma unroll
      for (int mr=0;mr<2;++mr)
        #pragma unroll
        for (int nr=0;nr<2;++nr)
          sacc[mr][nr] = __builtin_amdgcn_mfma_f32_16x16x32_bf16(af[mr], bfr[nr], sacc[mr][nr], 0,0,0);
    }
    #pragma unroll
    for (int mr=0;mr<2;++mr)
      #pragma unroll
      for (int nr=0;nr<2;++nr)
        #pragma unroll
        for (int i=0;i<4;++i) {
          int row = wr*32+mr*16+lk*4+i, col = wc*32+nr*16+lr;
          float p = __expf(sacc[mr][nr][i]*SCALE_);
          ds[mr*4+i] += p;
          Ptl[row][SWZE(row, col)] = f2b(p);
        }
    __syncthreads();
    #pragma unroll
    for (int ks=0; ks<2; ++ks) {
      bf16x8 af2[2], bf2[2];
      #pragma unroll
      for (int mr=0;mr<2;++mr){ int r = wr*32+mr*16+lr; af2[mr] = *(const bf16x8*)&Ptl[r][SWZ(r, ks*4+lk)]; }
      #pragma unroll
      for (int nr=0;nr<2;++nr){ int r = wc*32+nr*16+lr; bf2[nr] = *(const bf16x8*)&Vtt[r][SWZ(r, ks*4+lk)]; }
      #pragma unroll
      for (int mr=0;mr<2;++mr)
        #pragma unroll
        for (int nr=0;nr<2;++nr)
          pacc[mr][nr] = __builtin_amdgcn_mfma_f32_16x16x32_bf16(af2[mr], bf2[nr], pacc[mr][nr], 0,0,0);
    }
  }
  float* dst = pacc_part + ((long)bh*LSPLIT + ch) * 4096;
  #pragma unroll
  for (int mr=0;mr<2;++mr)
    #pragma unroll
    for (int nr=0;nr<2;++nr)
      #pragma unroll
      for (int i=0;i<4;++i) {
        int row = wr*32+mr*16+lk*4+i, col = wc*32+nr*16+lr;
        dst[row*64+col] = pacc[mr][nr][i];
      }
  #pragma unroll
  for (int o=1;o<16;o<<=1)
    #pragma unroll
    for (int j=0;j<8;++j) ds[j] += __shfl_xor(ds[j], o);
  if (lr == 0) {
    #pragma unroll
    for (int mr=0;mr<2;++mr)
      #pragma unroll
      for (int i=0;i<4;++i)
        dsh[wc][wr*32+mr*16+lk*4+i] = ds[mr*4+i];
  }
  __syncthreads();
  if (tid < 64)
    dsum_part[((long)bh*LSPLIT + ch)*64 + tid] = dsh[0][tid] + dsh[1][tid];
}

// ================= reduce flash partials -> R2t =================
__global__ __launch_bounds__(256) void reduce_R2(
    const float* __restrict__ pacc_part, const float* __restrict__ dsum_part,
    bfu* __restrict__ R2t)
{
  int idx = blockIdx.x * 256 + threadIdx.x;
  int bh = idx >> 12, s = (idx >> 6) & 63, d = idx & 63;
  int b = bh / NH, hh = bh % NH;
  float pa = 0.f, dsv = 0.f;
  #pragma unroll
  for (int c = 0; c < LSPLIT; ++c) {
    pa += pacc_part[((long)bh*LSPLIT + c)*4096 + (s<<6) + d];
    dsv += dsum_part[((long)bh*LSPLIT + c)*64 + s];
  }
  R2t[(((long)b*DI) + hh*HD + d)*64 + s] = f2b(pa / dsv);
}

// ================= y = fine + V*D ; LN ; *z (vectorized, wave/pixel) =================
__global__ __launch_bounds__(256) void ln_kernel(
    const bfu* __restrict__ fine, const bfu* __restrict__ xB2,
    const bfu* __restrict__ z, const float* __restrict__ Dv,
    const float* __restrict__ ln_g, const float* __restrict__ ln_b,
    bfu* __restrict__ yn)
{
  const int p = blockIdx.x*4 + (threadIdx.x >> 6);
  const int lane = threadIdx.x & 63;
  float v[8]; float s = 0.f, ss = 0.f;
  if (lane < 48) {
    u16x8 fv = *(const u16x8*)(fine + (long)p*DI + lane*8);
    u16x8 xv = *(const u16x8*)(xB2 + (long)p*CD + lane*8);
    const float dv = Dv[lane >> 3];
    #pragma unroll
    for (int j=0;j<8;++j) {
      float f = b2f((bfu)fv[j]) + b2f((bfu)xv[j]) * dv;
      v[j] = f; s += f; ss += f*f;
    }
  }
  #pragma unroll
  for (int o = 32; o; o >>= 1) { s += __shfl_xor(s, o); ss += __shfl_xor(ss, o); }
  float mu = s * (1.f/384.f);
  float var = ss * (1.f/384.f) - mu*mu;
  float rs = rsqrtf(var + 1e-5f);
  if (lane < 48) {
    u16x8 zv = *(const u16x8*)(z + (long)p*DI + lane*8);
    float4 g0 = ld4(ln_g + lane*8), g1 = ld4(ln_g + lane*8 + 4);
    float4 b0 = ld4(ln_b + lane*8), b1 = ld4(ln_b + lane*8 + 4);
    float g[8] = {g0.x,g0.y,g0.z,g0.w,g1.x,g1.y,g1.z,g1.w};
    float bb[8] = {b0.x,b0.y,b0.z,b0.w,b1.x,b1.y,b1.z,b1.w};
    u16x8 ov;
    #pragma unroll
    for (int j=0;j<8;++j) {
      float o2 = (v[j] - mu) * rs * g[j] + bb[j];
      ov[j] = f2b(o2 * b2f((bfu)zv[j]));
    }
    *(u16x8*)(yn + (long)p*DI + lane*8) = ov;
  }
}

extern "C" void kernel_launch(void* const* d_in, const int* in_sizes, int n_in,
                              void* d_out, int out_size, void* d_ws, size_t ws_size,
                              hipStream_t stream) {
  const float* u      = (const float*)d_in[0];
  const float* W_in   = (const float*)d_in[1];
  const float* conv_w = (const float*)d_in[2];
  const float* conv_b = (const float*)d_in[3];
  const float* dw_w   = (const float*)d_in[4];
  const float* dw_b   = (const float*)d_in[5];
  const float* pw_w   = (const float*)d_in[6];
  const float* pw_b   = (const float*)d_in[7];
  const float* Dv     = (const float*)d_in[8];
  const float* ln_g   = (const float*)d_in[9];
  const float* ln_b   = (const float*)d_in[10];
  const float* W_out  = (const float*)d_in[11];
  float* out = (float*)d_out;

  bfu* z_bf = (bfu*)d_out;      // M_*384 bf16 == out_size*4 bytes, dead before final write

  char* ws = (char*)d_ws;
  size_t off = 0;
  bfu* xB_bf   = (bfu*)(ws + off); off += (size_t)M_*CD*2;   // gemm1 cols 384..; later fine
  bfu* xB2_bf  = (bfu*)(ws + off); off += (size_t)M_*CD*2;   // conv3 out, live to LN
  bfu* xloc_bf = (bfu*)(ws + off); off += (size_t)M_*DI*2;   // u_bf / conv5 out / part / yn
  bfu* Vs_bf   = (bfu*)(ws + off); off += (size_t)M_*DI*2;
  bfu* Ksf_bf  = (bfu*)(ws + off); off += (size_t)M_*DS*2;
  bfu* Wt_in   = (bfu*)(ws + off); off += (size_t)832*192*2;
  bfu* pw_bf   = (bfu*)(ws + off); off += (size_t)384*384*2;
  bfu* Wt_out  = (bfu*)(ws + off); off += (size_t)192*384*2;
  bfu* R2t     = (bfu*)(ws + off); off += (size_t)8*DI*64*2;
  bfu* proto_b = (bfu*)(ws + off); off += (size_t)48*4096*2;
  bfu*   u_bf  = xloc_bf;
  float* part  = (float*)xloc_bf;
  float* dsum  = part + (size_t)48*LSPLIT*4096;

  bfu* fine_bf = xB_bf;
  bfu* yn_bf   = xloc_bf;

  // 0) prep
  prep_w<<<1488, 256, 0, stream>>>(W_in, pw_w, W_out, Wt_in, pw_bf, Wt_out);
  conv_u<<<(M_*DM/8 + 255)/256, 256, 0, stream>>>(u, u_bf);
  // 1) zxB = u @ W_in
  gemm_mfma<false,bfu,bfu><<<dim3(13,576,1), 256, 0, stream>>>(
      u_bf, Wt_in, nullptr, z_bf, xB_bf, 192, 384, 384, 448, 0, 0, 0);
  // 2) depthwise 3x3 + silu (32 ch/block)
  conv_dw<3,CD,CD,true><<<dim3(36,14,8), 256, 0, stream>>>(xB_bf, conv_w, conv_b, xB2_bf);
  // 2b) K_soft
  ksoft_kernel<<<M_/4, 256, 0, stream>>>(xB2_bf, Ksf_bf);
  // 3) depthwise 5x5 (32 ch/block)
  conv_dw<5,CD,DI,false><<<dim3(36,12,8), 256, 0, stream>>>(xB2_bf, dw_w, dw_b, xloc_bf);
  // 4) pointwise: Vs = xloc @ pw_w^T + pw_b
  gemm_mfma<true,bfu,bfu><<<dim3(6,576,1), 256, 0, stream>>>(
      xloc_bf, pw_bf, pw_b, Vs_bf, (bfu*)nullptr, 384, 1<<30, 384, 0, 0, 0, 0);
  // 5) proto
  proto_mfma<<<dim3(LSPLIT,48), 256, 0, stream>>>(Ksf_bf, Vs_bf, part);
  reduce_proto<<<768, 256, 0, stream>>>(part, proto_b);
  // 6) flash attention
  flashpv_mfma<<<dim3(LSPLIT,48), 256, 0, stream>>>(proto_b, Vs_bf, part, dsum);
  reduce_R2<<<768, 256, 0, stream>>>(part, dsum, R2t);
  // 7) fine = Ksoft @ refined^T
  gemm_mfma<false,bfu,bfu><<<dim3(6,72,8), 256, 0, stream>>>(
      Ksf_bf, R2t, nullptr, fine_bf, (bfu*)nullptr, 64, 1<<30, 384, 0,
      (long)L_*64, (long)DI*64, (long)L_*384);
  // 8) y = fine + V*D ; LN ; *z
  ln_kernel<<<M_/4, 256, 0, stream>>>(fine_bf, xB2_bf, z_bf, Dv, ln_g, ln_b, yn_bf);
  // 9) out = yn @ W_out
  gemm_mfma<false,float,float><<<dim3(3,576,1), 256, 0, stream>>>(
      yn_bf, Wt_out, nullptr, out, (float*)nullptr, 384, 1<<30, 192, 0, 0, 0, 0);
}